// Round 13
// baseline (1038.846 us; speedup 1.0000x reference)
//
#include <hip/hip_runtime.h>
#include <hip/hip_bf16.h>
#include <math.h>

#define DIM 64
#define NBK_MAX 512       // max 256-node buckets (N <= 131072)
#define PCHUNK 4096
typedef _Float16 f16;
typedef unsigned int uint32;

__device__ __forceinline__ float bcast(float v, int k) {
  return __uint_as_float(__builtin_amdgcn_readlane(__float_as_uint(v), k));
}

// ---------------- histogram over 256-node target buckets ----------------
__global__ __launch_bounds__(256) void k_hist(const int* __restrict__ col, int* __restrict__ bkcnt,
                                              int E, int nbk) {
  __shared__ int lc[NBK_MAX];
  int tid = threadIdx.x;
  for (int i = tid; i < nbk; i += 256) lc[i] = 0;
  __syncthreads();
  int b0 = blockIdx.x * PCHUNK;
  int b1 = min(E, b0 + PCHUNK);
  for (int e = b0 + tid; e < b1; e += 256) atomicAdd(&lc[col[e] >> 8], 1);
  __syncthreads();
  for (int i = tid; i < nbk; i += 256) { int c = lc[i]; if (c) atomicAdd(&bkcnt[i], c); }
}

// ---------------- exclusive scan over nbk bucket counts (single block) ----------------
__global__ __launch_bounds__(256) void k_scank(const int* __restrict__ cnt, int* __restrict__ offs,
                                               int* __restrict__ cur, int nbk) {
  __shared__ int ps[256];
  int t = threadIdx.x;
  int per = (nbk + 255) >> 8;
  int b0 = t * per;
  int s = 0;
  for (int i = 0; i < per; ++i) { int idx = b0 + i; if (idx < nbk) s += cnt[idx]; }
  ps[t] = s;
  __syncthreads();
  for (int d = 1; d < 256; d <<= 1) {
    int v = (t >= d) ? ps[t - d] : 0;
    __syncthreads();
    if (t >= d) ps[t] += v;
    __syncthreads();
  }
  int run = ps[t] - s;
  for (int i = 0; i < per; ++i) {
    int idx = b0 + i;
    if (idx < nbk) { offs[idx] = run; cur[idx] = run; run += cnt[idx]; }
  }
  if (t == 255) offs[nbk] = run;   // == E
}

// ---------------- partition edges into 256-node-bucket segments ----------------
__global__ __launch_bounds__(256) void k_part(const int* __restrict__ row, const int* __restrict__ col,
                                              int* __restrict__ bcur, uint32* __restrict__ recs,
                                              int E, int nbk) {
  __shared__ int lc[NBK_MAX];
  __shared__ int gb[NBK_MAX];
  int tid = threadIdx.x;
  for (int i = tid; i < nbk; i += 256) lc[i] = 0;
  __syncthreads();
  int b0 = blockIdx.x * PCHUNK;
  int b1 = min(E, b0 + PCHUNK);
  for (int e = b0 + tid; e < b1; e += 256) atomicAdd(&lc[col[e] >> 8], 1);
  __syncthreads();
  for (int i = tid; i < nbk; i += 256) {
    int c = lc[i];
    if (c) { gb[i] = atomicAdd(&bcur[i], c); lc[i] = 0; }
  }
  __syncthreads();
  for (int e = b0 + tid; e < b1; e += 256) {
    int r = row[e], c = col[e];
    int k = c >> 8;
    int pos = gb[k] + atomicAdd(&lc[k], 1);
    recs[pos] = ((uint32)r << 8) | (uint32)(c & 255);
  }
}

// ---------------- per-bucket counting sort -> per-node CSR + deg + dis ----------------
__global__ __launch_bounds__(256) void k_sort2(const uint32* __restrict__ recs, const int* __restrict__ keyoffs,
                                               int* __restrict__ csrs, int* __restrict__ offs,
                                               int* __restrict__ cnt, float* __restrict__ dis, int N) {
  __shared__ int lc[256];
  __shared__ int ps[256];
  __shared__ int pos[256];
  int b = blockIdx.x, tid = threadIdx.x;
  lc[tid] = 0;
  __syncthreads();
  int beg = keyoffs[b], end = keyoffs[b + 1];
  for (int p = beg + tid; p < end; p += 256) atomicAdd(&lc[recs[p] & 255], 1);
  __syncthreads();
  int my = lc[tid];
  ps[tid] = my;
  __syncthreads();
  for (int d = 1; d < 256; d <<= 1) {
    int v = (tid >= d) ? ps[tid - d] : 0;
    __syncthreads();
    if (tid >= d) ps[tid] += v;
    __syncthreads();
  }
  int epf = ps[tid] - my;
  pos[tid] = beg + epf;
  int node = (b << 8) + tid;
  if (node < N) {
    offs[node] = beg + epf;
    cnt[node] = my;
    dis[node] = rsqrtf((float)(my + 1));
  }
  __syncthreads();
  for (int p = beg + tid; p < end; p += 256) {
    uint32 r = recs[p];
    int q = atomicAdd(&pos[r & 255], 1);
    csrs[q] = (int)(r >> 8);
  }
}

// ---------------- GEMM layer 1: xl = dis * (x @ W1), readlane broadcast, no LDS ----------------
// FIN = 128 hardcoded. Thread j holds W1 column j (128 VGPRs).
__global__ __launch_bounds__(256) void k_gemm_in(const float* __restrict__ x, const float* __restrict__ W,
                                                 const float* __restrict__ dis, f16* __restrict__ xl, int N) {
  int tid = threadIdx.x;
  int lane = tid & 63, wave = tid >> 6;
  float w[128];
#pragma unroll
  for (int k = 0; k < 128; ++k) w[k] = W[k * DIM + lane];
  int stride = gridDim.x * 4;
  for (int n = blockIdx.x * 4 + wave; n < N; n += stride) {
    const float* xr = x + (size_t)n * 128;
    float x0 = xr[lane];
    float x1 = xr[64 + lane];
    float acc = 0.f;
#pragma unroll
    for (int k = 0; k < 64; ++k) acc = fmaf(bcast(x0, k), w[k], acc);
#pragma unroll
    for (int k = 0; k < 64; ++k) acc = fmaf(bcast(x1, k), w[64 + k], acc);
    xl[((uint32)n << 6) | lane] = (f16)(acc * dis[n]);
  }
}

// ---------------- GEMM layers 2-4: xl = dis * (bn(y) @ W), BN folded into W/cb, no LDS ----------------
__global__ __launch_bounds__(256) void k_gemm_bn(const f16* __restrict__ y16, const float* __restrict__ W,
                                                 const float* __restrict__ gam, const float* __restrict__ bet,
                                                 const float* __restrict__ s1, const float* __restrict__ s2,
                                                 const float* __restrict__ dis, f16* __restrict__ xl,
                                                 int N, float invN) {
  int tid = threadIdx.x;
  int lane = tid & 63, wave = tid >> 6;
  float w[64];
  float cb = 0.f;
#pragma unroll
  for (int k = 0; k < 64; ++k) {
    float m = s1[k] * invN;
    float var = s2[k] * invN - m * m;
    float a = gam[k] * rsqrtf(var + 1e-5f);
    float c = fmaf(-m, a, bet[k]);
    float wk = W[k * DIM + lane];
    w[k] = a * wk;
    cb = fmaf(c, wk, cb);
  }
  int stride = gridDim.x * 4;
  for (int n = blockIdx.x * 4 + wave; n < N; n += stride) {
    float yv = (float)y16[((uint32)n << 6) | lane];
    float acc = cb;
#pragma unroll
    for (int k = 0; k < 64; ++k) acc = fmaf(bcast(yv, k), w[k], acc);
    xl[((uint32)n << 6) | lane] = (f16)(acc * dis[n]);
  }
}

// ---------------- aggregation: per-node register accumulate, unroll 16, f16 y out ----------------
__global__ __launch_bounds__(256) void k_agg(const f16* __restrict__ xl, const int* __restrict__ offs,
                                             const int* __restrict__ cnt, const int* __restrict__ src,
                                             const float* __restrict__ dis, const float* __restrict__ bias,
                                             f16* __restrict__ y, float* __restrict__ s1,
                                             float* __restrict__ s2, int N) {
  int tid = threadIdx.x;
  int wave = tid >> 6, lane = tid & 63;
  float ls = 0.f, lq = 0.f;
  float b = bias[lane];
  int stride = gridDim.x * 4;
  for (int n = blockIdx.x * 4 + wave; n < N; n += stride) {
    float di = dis[n];
    float acc = (float)xl[((uint32)n << 6) | lane];  // self-loop (pre-scaled)
    int p = offs[n];
    int end = p + cnt[n];
    for (; p + 15 < end; p += 16) {
      float s = 0.f;
#pragma unroll
      for (int j = 0; j < 16; ++j) s += (float)xl[((uint32)src[p + j] << 6) | lane];
      acc += s;
    }
    for (; p < end; ++p) acc += (float)xl[((uint32)src[p] << 6) | lane];
    float yv = fmaxf(fmaf(di, acc, b), 0.f);
    y[((uint32)n << 6) | lane] = (f16)yv;
    ls += yv;
    lq = fmaf(yv, yv, lq);
  }
  __shared__ float rbuf[256];
  rbuf[tid] = ls;
  __syncthreads();
  if (tid < 64) atomicAdd(&s1[tid], rbuf[tid] + rbuf[tid + 64] + rbuf[tid + 128] + rbuf[tid + 192]);
  __syncthreads();
  rbuf[tid] = lq;
  __syncthreads();
  if (tid < 64) atomicAdd(&s2[tid], rbuf[tid] + rbuf[tid + 64] + rbuf[tid + 128] + rbuf[tid + 192]);
}

// ---------------- global mean pool: segmented (batch sorted), BN4 fused ----------------
__global__ __launch_bounds__(256) void k_pool(const f16* __restrict__ y, const float* __restrict__ gam,
                                              const float* __restrict__ bet, const float* __restrict__ s1,
                                              const float* __restrict__ s2, const int* __restrict__ batch,
                                              float* __restrict__ pooled, float* __restrict__ gcnt,
                                              int N, int chunk, float invN) {
  __shared__ float aL[DIM], cL[DIM];
  int tid = threadIdx.x;
  if (tid < DIM) {
    float m = s1[tid] * invN;
    float var = s2[tid] * invN - m * m;
    float inv = rsqrtf(var + 1e-5f);
    float a = gam[tid] * inv;
    aL[tid] = a;
    cL[tid] = fmaf(-m, a, bet[tid]);
  }
  __syncthreads();
  int wave = tid >> 6, lane = tid & 63;
  int wid = blockIdx.x * 4 + wave;
  int n0 = wid * chunk;
  int n1 = min(N, n0 + chunk);
  if (n0 >= N) return;
  float aV = aL[lane], cV = cL[lane];
  int cur_g = batch[n0];
  float acc = 0.f;
  int cntn = 0;
  for (int n = n0; n < n1; ++n) {
    int gi = batch[n];
    if (gi != cur_g) {
      atomicAdd(&pooled[(size_t)cur_g * DIM + lane], acc);
      if (lane == 0) atomicAdd(&gcnt[cur_g], (float)cntn);
      cur_g = gi; acc = 0.f; cntn = 0;
    }
    acc += fmaf(aV, (float)y[((uint32)n << 6) | lane], cV);
    ++cntn;
  }
  atomicAdd(&pooled[(size_t)cur_g * DIM + lane], acc);
  if (lane == 0) atomicAdd(&gcnt[cur_g], (float)cntn);
}

// ---------------- head: mean, fc, log_softmax ----------------
__global__ __launch_bounds__(256) void k_head(const float* __restrict__ pooled, const float* __restrict__ gcnt,
                                              const float* __restrict__ fcW, const float* __restrict__ fcb,
                                              float* __restrict__ out, int G, int C) {
  int g = blockIdx.x * 256 + threadIdx.x;
  if (g >= G) return;
  float z[16];
  for (int c = 0; c < C; ++c) z[c] = fcb[c];
  float inv = 1.f / fmaxf(gcnt[g], 1.f);
  for (int f = 0; f < DIM; ++f) {
    float p = pooled[(size_t)g * DIM + f] * inv;
    for (int c = 0; c < C; ++c) z[c] = fmaf(p, fcW[f * C + c], z[c]);
  }
  float m = -1e30f;
  for (int c = 0; c < C; ++c) m = fmaxf(m, z[c]);
  float s = 0.f;
  for (int c = 0; c < C; ++c) s += expf(z[c] - m);
  float ls = logf(s);
  for (int c = 0; c < C; ++c) out[(size_t)g * C + c] = z[c] - m - ls;
}

extern "C" void kernel_launch(void* const* d_in, const int* in_sizes, int n_in,
                              void* d_out, int out_size, void* d_ws, size_t ws_size,
                              hipStream_t stream) {
  const float* x    = (const float*)d_in[0];
  const int*   ei   = (const int*)d_in[1];
  const int*   batch= (const int*)d_in[2];
  const float* W1 = (const float*)d_in[4];
  const float* b1 = (const float*)d_in[5];
  const float* W2 = (const float*)d_in[6];
  const float* b2 = (const float*)d_in[7];
  const float* W3 = (const float*)d_in[8];
  const float* b3 = (const float*)d_in[9];
  const float* W4 = (const float*)d_in[10];
  const float* b4 = (const float*)d_in[11];
  const float* g1 = (const float*)d_in[12];
  const float* be1= (const float*)d_in[13];
  const float* g2 = (const float*)d_in[14];
  const float* be2= (const float*)d_in[15];
  const float* g3 = (const float*)d_in[16];
  const float* be3= (const float*)d_in[17];
  const float* g4 = (const float*)d_in[18];
  const float* be4= (const float*)d_in[19];
  const float* fcW= (const float*)d_in[20];
  const float* fcb= (const float*)d_in[21];
  float* out = (float*)d_out;

  int N   = in_sizes[2];
  int E   = in_sizes[1] / 2;
  int C   = in_sizes[21];
  int G   = out_size / C;
  float invN = 1.0f / (float)N;

  int nbk = (N + 255) >> 8;       // 256-node target buckets

  char* ws = (char*)d_ws;
  size_t off = 0;
  auto alloc = [&](size_t bytes) { size_t o = off; off = (off + bytes + 255) & ~(size_t)255; return o; };
  // zero-init group (must be first / contiguous)
  size_t o_bkc  = alloc((size_t)nbk * 4);
  size_t o_bn   = alloc(4 * 2 * 64 * 4);
  size_t o_pool = alloc((size_t)G * DIM * 4);
  size_t o_gcnt = alloc((size_t)G * 4);
  size_t zero_bytes = off;
  // no-init group
  size_t o_ko   = alloc((size_t)(nbk + 1) * 4);
  size_t o_cur  = alloc((size_t)nbk * 4);
  size_t o_offs = alloc((size_t)N * 4);
  size_t o_cnt  = alloc((size_t)N * 4);
  size_t o_dis  = alloc((size_t)N * 4);
  size_t o_recs = alloc((size_t)E * 4);
  size_t o_csr  = alloc((size_t)E * 4);
  size_t o_xl   = alloc((size_t)N * DIM * 2);   // fp16
  size_t o_y    = alloc((size_t)N * DIM * 2);   // fp16
  (void)ws_size;

  int*    bkcnt  = (int*)(ws + o_bkc);
  float*  bn     = (float*)(ws + o_bn);
  float*  pooled = (float*)(ws + o_pool);
  float*  gcnt   = (float*)(ws + o_gcnt);
  int*    keyoffs= (int*)(ws + o_ko);
  int*    bcur   = (int*)(ws + o_cur);
  int*    offs   = (int*)(ws + o_offs);
  int*    cnt    = (int*)(ws + o_cnt);
  float*  dis    = (float*)(ws + o_dis);
  uint32* recs   = (uint32*)(ws + o_recs);
  int*    csrs   = (int*)(ws + o_csr);
  f16*    xl     = (f16*)(ws + o_xl);
  f16*    y      = (f16*)(ws + o_y);

  hipMemsetAsync(d_ws, 0, zero_bytes, stream);

  const int* row  = ei;
  const int* colp = ei + E;
  int pblk = (E + PCHUNK - 1) / PCHUNK;

  k_hist<<<pblk, 256, 0, stream>>>(colp, bkcnt, E, nbk);
  k_scank<<<1, 256, 0, stream>>>(bkcnt, keyoffs, bcur, nbk);
  k_part<<<pblk, 256, 0, stream>>>(row, colp, bcur, recs, E, nbk);
  k_sort2<<<nbk, 256, 0, stream>>>(recs, keyoffs, csrs, offs, cnt, dis, N);

  // Layer 1
  k_gemm_in<<<2048, 256, 0, stream>>>(x, W1, dis, xl, N);
  k_agg<<<2048, 256, 0, stream>>>(xl, offs, cnt, csrs, dis, b1, y, bn + 0, bn + 64, N);
  // Layer 2 (applies BN1 via folded W)
  k_gemm_bn<<<2048, 256, 0, stream>>>(y, W2, g1, be1, bn + 0, bn + 64, dis, xl, N, invN);
  k_agg<<<2048, 256, 0, stream>>>(xl, offs, cnt, csrs, dis, b2, y, bn + 128, bn + 192, N);
  // Layer 3
  k_gemm_bn<<<2048, 256, 0, stream>>>(y, W3, g2, be2, bn + 128, bn + 192, dis, xl, N, invN);
  k_agg<<<2048, 256, 0, stream>>>(xl, offs, cnt, csrs, dis, b3, y, bn + 256, bn + 320, N);
  // Layer 4
  k_gemm_bn<<<2048, 256, 0, stream>>>(y, W4, g3, be3, bn + 256, bn + 320, dis, xl, N, invN);
  k_agg<<<2048, 256, 0, stream>>>(xl, offs, cnt, csrs, dis, b4, y, bn + 384, bn + 448, N);
  // Pool (applies BN4) + head
  int nwaves = 2048;
  int chunk = (N + nwaves - 1) / nwaves;
  k_pool<<<nwaves / 4, 256, 0, stream>>>(y, g4, be4, bn + 384, bn + 448, batch, pooled, gcnt, N, chunk, invN);
  k_head<<<(G + 255) / 256, 256, 0, stream>>>(pooled, gcnt, fcW, fcb, out, G, C);
}

// Round 14
// 961.370 us; speedup vs baseline: 1.0806x; 1.0806x over previous
//
#include <hip/hip_runtime.h>
#include <hip/hip_bf16.h>
#include <math.h>

#define DIM 64
#define NBK_MAX 512       // max 256-node buckets (N <= 131072)
#define PCHUNK 4096
typedef _Float16 f16;
typedef unsigned int uint32;

__device__ __forceinline__ float bcast(float v, int k) {
  return __uint_as_float(__builtin_amdgcn_readlane(__float_as_uint(v), k));
}

// ---------------- histogram over 256-node target buckets ----------------
__global__ __launch_bounds__(256) void k_hist(const int* __restrict__ col, int* __restrict__ bkcnt,
                                              int E, int nbk) {
  __shared__ int lc[NBK_MAX];
  int tid = threadIdx.x;
  for (int i = tid; i < nbk; i += 256) lc[i] = 0;
  __syncthreads();
  int b0 = blockIdx.x * PCHUNK;
  int b1 = min(E, b0 + PCHUNK);
  for (int e = b0 + tid; e < b1; e += 256) atomicAdd(&lc[col[e] >> 8], 1);
  __syncthreads();
  for (int i = tid; i < nbk; i += 256) { int c = lc[i]; if (c) atomicAdd(&bkcnt[i], c); }
}

// ---------------- exclusive scan over nbk bucket counts (single block) ----------------
__global__ __launch_bounds__(256) void k_scank(const int* __restrict__ cnt, int* __restrict__ offs,
                                               int* __restrict__ cur, int nbk) {
  __shared__ int ps[256];
  int t = threadIdx.x;
  int per = (nbk + 255) >> 8;
  int b0 = t * per;
  int s = 0;
  for (int i = 0; i < per; ++i) { int idx = b0 + i; if (idx < nbk) s += cnt[idx]; }
  ps[t] = s;
  __syncthreads();
  for (int d = 1; d < 256; d <<= 1) {
    int v = (t >= d) ? ps[t - d] : 0;
    __syncthreads();
    if (t >= d) ps[t] += v;
    __syncthreads();
  }
  int run = ps[t] - s;
  for (int i = 0; i < per; ++i) {
    int idx = b0 + i;
    if (idx < nbk) { offs[idx] = run; cur[idx] = run; run += cnt[idx]; }
  }
  if (t == 255) offs[nbk] = run;   // == E
}

// ---------------- partition edges into 256-node-bucket segments ----------------
__global__ __launch_bounds__(256) void k_part(const int* __restrict__ row, const int* __restrict__ col,
                                              int* __restrict__ bcur, uint32* __restrict__ recs,
                                              int E, int nbk) {
  __shared__ int lc[NBK_MAX];
  __shared__ int gb[NBK_MAX];
  int tid = threadIdx.x;
  for (int i = tid; i < nbk; i += 256) lc[i] = 0;
  __syncthreads();
  int b0 = blockIdx.x * PCHUNK;
  int b1 = min(E, b0 + PCHUNK);
  for (int e = b0 + tid; e < b1; e += 256) atomicAdd(&lc[col[e] >> 8], 1);
  __syncthreads();
  for (int i = tid; i < nbk; i += 256) {
    int c = lc[i];
    if (c) { gb[i] = atomicAdd(&bcur[i], c); lc[i] = 0; }
  }
  __syncthreads();
  for (int e = b0 + tid; e < b1; e += 256) {
    int r = row[e], c = col[e];
    int k = c >> 8;
    int pos = gb[k] + atomicAdd(&lc[k], 1);
    recs[pos] = ((uint32)r << 8) | (uint32)(c & 255);
  }
}

// ---------------- per-bucket counting sort -> per-node CSR + deg + dis ----------------
__global__ __launch_bounds__(256) void k_sort2(const uint32* __restrict__ recs, const int* __restrict__ keyoffs,
                                               int* __restrict__ csrs, int* __restrict__ offs,
                                               int* __restrict__ cnt, float* __restrict__ dis, int N) {
  __shared__ int lc[256];
  __shared__ int ps[256];
  __shared__ int pos[256];
  int b = blockIdx.x, tid = threadIdx.x;
  lc[tid] = 0;
  __syncthreads();
  int beg = keyoffs[b], end = keyoffs[b + 1];
  for (int p = beg + tid; p < end; p += 256) atomicAdd(&lc[recs[p] & 255], 1);
  __syncthreads();
  int my = lc[tid];
  ps[tid] = my;
  __syncthreads();
  for (int d = 1; d < 256; d <<= 1) {
    int v = (tid >= d) ? ps[tid - d] : 0;
    __syncthreads();
    if (tid >= d) ps[tid] += v;
    __syncthreads();
  }
  int epf = ps[tid] - my;
  pos[tid] = beg + epf;
  int node = (b << 8) + tid;
  if (node < N) {
    offs[node] = beg + epf;
    cnt[node] = my;
    dis[node] = rsqrtf((float)(my + 1));
  }
  __syncthreads();
  for (int p = beg + tid; p < end; p += 256) {
    uint32 r = recs[p];
    int q = atomicAdd(&pos[r & 255], 1);
    csrs[q] = (int)(r >> 8);
  }
}

// ---------------- GEMM layer 1: xl = dis * (x @ W1), readlane broadcast, no LDS ----------------
__global__ __launch_bounds__(256) void k_gemm_in(const float* __restrict__ x, const float* __restrict__ W,
                                                 const float* __restrict__ dis, f16* __restrict__ xl, int N) {
  int tid = threadIdx.x;
  int lane = tid & 63, wave = tid >> 6;
  float w[128];
#pragma unroll
  for (int k = 0; k < 128; ++k) w[k] = W[k * DIM + lane];
  int stride = gridDim.x * 4;
  for (int n = blockIdx.x * 4 + wave; n < N; n += stride) {
    const float* xr = x + (size_t)n * 128;
    float x0 = xr[lane];
    float x1 = xr[64 + lane];
    float acc = 0.f;
#pragma unroll
    for (int k = 0; k < 64; ++k) acc = fmaf(bcast(x0, k), w[k], acc);
#pragma unroll
    for (int k = 0; k < 64; ++k) acc = fmaf(bcast(x1, k), w[64 + k], acc);
    xl[((uint32)n << 6) | lane] = (f16)(acc * dis[n]);
  }
}

// ---------------- GEMM layers 2-4: xl = dis * (bn(y) @ W), BN folded into W/cb, no LDS ----------------
__global__ __launch_bounds__(256) void k_gemm_bn(const f16* __restrict__ y16, const float* __restrict__ W,
                                                 const float* __restrict__ gam, const float* __restrict__ bet,
                                                 const float* __restrict__ s1, const float* __restrict__ s2,
                                                 const float* __restrict__ dis, f16* __restrict__ xl,
                                                 int N, float invN) {
  int tid = threadIdx.x;
  int lane = tid & 63, wave = tid >> 6;
  float w[64];
  float cb = 0.f;
#pragma unroll
  for (int k = 0; k < 64; ++k) {
    float m = s1[k] * invN;
    float var = s2[k] * invN - m * m;
    float a = gam[k] * rsqrtf(var + 1e-5f);
    float c = fmaf(-m, a, bet[k]);
    float wk = W[k * DIM + lane];
    w[k] = a * wk;
    cb = fmaf(c, wk, cb);
  }
  int stride = gridDim.x * 4;
  for (int n = blockIdx.x * 4 + wave; n < N; n += stride) {
    float yv = (float)y16[((uint32)n << 6) | lane];
    float acc = cb;
#pragma unroll
    for (int k = 0; k < 64; ++k) acc = fmaf(bcast(yv, k), w[k], acc);
    xl[((uint32)n << 6) | lane] = (f16)(acc * dis[n]);
  }
}

// ---------------- aggregation: ping-pong software-pipelined 8-wide gather ----------------
#define LOAD8(dst, pp) \
  { _Pragma("unroll") for (int j = 0; j < 8; ++j) dst[j] = xl[((uint32)src[(pp) + j] << 6) | lane]; }
#define SUM8(dst) (((float)dst[0] + (float)dst[1]) + ((float)dst[2] + (float)dst[3])) + \
                  (((float)dst[4] + (float)dst[5]) + ((float)dst[6] + (float)dst[7]))

__global__ __launch_bounds__(256) void k_agg(const f16* __restrict__ xl, const int* __restrict__ offs,
                                             const int* __restrict__ cnt, const int* __restrict__ src,
                                             const float* __restrict__ dis, const float* __restrict__ bias,
                                             f16* __restrict__ y, float* __restrict__ s1,
                                             float* __restrict__ s2, int N) {
  int tid = threadIdx.x;
  int wave = tid >> 6, lane = tid & 63;
  float ls = 0.f, lq = 0.f;
  float b = bias[lane];
  int stride = gridDim.x * 4;
  for (int n = blockIdx.x * 4 + wave; n < N; n += stride) {
    float di = dis[n];
    float self = (float)xl[((uint32)n << 6) | lane];  // independent; overlaps with gathers
    int p = offs[n];
    int end = p + cnt[n];
    float acc = 0.f;
    if (p + 8 <= end) {
      f16 A[8], B[8];
      LOAD8(A, p); p += 8;
      while (p + 16 <= end) {
        LOAD8(B, p);            // issue B while A's data settles
        acc += SUM8(A);         // consumes A only -> compiler waits vmcnt(>0), B stays in flight
        p += 8;
        LOAD8(A, p);
        acc += SUM8(B);
        p += 8;
      }
      if (p + 8 <= end) {
        LOAD8(B, p);
        acc += SUM8(A);
        p += 8;
        acc += SUM8(B);
      } else {
        acc += SUM8(A);
      }
    }
    for (; p < end; ++p) acc += (float)xl[((uint32)src[p] << 6) | lane];
    acc += self;
    float yv = fmaxf(fmaf(di, acc, b), 0.f);
    y[((uint32)n << 6) | lane] = (f16)yv;
    ls += yv;
    lq = fmaf(yv, yv, lq);
  }
  __shared__ float rbuf[256];
  rbuf[tid] = ls;
  __syncthreads();
  if (tid < 64) atomicAdd(&s1[tid], rbuf[tid] + rbuf[tid + 64] + rbuf[tid + 128] + rbuf[tid + 192]);
  __syncthreads();
  rbuf[tid] = lq;
  __syncthreads();
  if (tid < 64) atomicAdd(&s2[tid], rbuf[tid] + rbuf[tid + 64] + rbuf[tid + 128] + rbuf[tid + 192]);
}

// ---------------- global mean pool: segmented (batch sorted), BN4 fused ----------------
__global__ __launch_bounds__(256) void k_pool(const f16* __restrict__ y, const float* __restrict__ gam,
                                              const float* __restrict__ bet, const float* __restrict__ s1,
                                              const float* __restrict__ s2, const int* __restrict__ batch,
                                              float* __restrict__ pooled, float* __restrict__ gcnt,
                                              int N, int chunk, float invN) {
  __shared__ float aL[DIM], cL[DIM];
  int tid = threadIdx.x;
  if (tid < DIM) {
    float m = s1[tid] * invN;
    float var = s2[tid] * invN - m * m;
    float inv = rsqrtf(var + 1e-5f);
    float a = gam[tid] * inv;
    aL[tid] = a;
    cL[tid] = fmaf(-m, a, bet[tid]);
  }
  __syncthreads();
  int wave = tid >> 6, lane = tid & 63;
  int wid = blockIdx.x * 4 + wave;
  int n0 = wid * chunk;
  int n1 = min(N, n0 + chunk);
  if (n0 >= N) return;
  float aV = aL[lane], cV = cL[lane];
  int cur_g = batch[n0];
  float acc = 0.f;
  int cntn = 0;
  for (int n = n0; n < n1; ++n) {
    int gi = batch[n];
    if (gi != cur_g) {
      atomicAdd(&pooled[(size_t)cur_g * DIM + lane], acc);
      if (lane == 0) atomicAdd(&gcnt[cur_g], (float)cntn);
      cur_g = gi; acc = 0.f; cntn = 0;
    }
    acc += fmaf(aV, (float)y[((uint32)n << 6) | lane], cV);
    ++cntn;
  }
  atomicAdd(&pooled[(size_t)cur_g * DIM + lane], acc);
  if (lane == 0) atomicAdd(&gcnt[cur_g], (float)cntn);
}

// ---------------- head: mean, fc, log_softmax ----------------
__global__ __launch_bounds__(256) void k_head(const float* __restrict__ pooled, const float* __restrict__ gcnt,
                                              const float* __restrict__ fcW, const float* __restrict__ fcb,
                                              float* __restrict__ out, int G, int C) {
  int g = blockIdx.x * 256 + threadIdx.x;
  if (g >= G) return;
  float z[16];
  for (int c = 0; c < C; ++c) z[c] = fcb[c];
  float inv = 1.f / fmaxf(gcnt[g], 1.f);
  for (int f = 0; f < DIM; ++f) {
    float p = pooled[(size_t)g * DIM + f] * inv;
    for (int c = 0; c < C; ++c) z[c] = fmaf(p, fcW[f * C + c], z[c]);
  }
  float m = -1e30f;
  for (int c = 0; c < C; ++c) m = fmaxf(m, z[c]);
  float s = 0.f;
  for (int c = 0; c < C; ++c) s += expf(z[c] - m);
  float ls = logf(s);
  for (int c = 0; c < C; ++c) out[(size_t)g * C + c] = z[c] - m - ls;
}

extern "C" void kernel_launch(void* const* d_in, const int* in_sizes, int n_in,
                              void* d_out, int out_size, void* d_ws, size_t ws_size,
                              hipStream_t stream) {
  const float* x    = (const float*)d_in[0];
  const int*   ei   = (const int*)d_in[1];
  const int*   batch= (const int*)d_in[2];
  const float* W1 = (const float*)d_in[4];
  const float* b1 = (const float*)d_in[5];
  const float* W2 = (const float*)d_in[6];
  const float* b2 = (const float*)d_in[7];
  const float* W3 = (const float*)d_in[8];
  const float* b3 = (const float*)d_in[9];
  const float* W4 = (const float*)d_in[10];
  const float* b4 = (const float*)d_in[11];
  const float* g1 = (const float*)d_in[12];
  const float* be1= (const float*)d_in[13];
  const float* g2 = (const float*)d_in[14];
  const float* be2= (const float*)d_in[15];
  const float* g3 = (const float*)d_in[16];
  const float* be3= (const float*)d_in[17];
  const float* g4 = (const float*)d_in[18];
  const float* be4= (const float*)d_in[19];
  const float* fcW= (const float*)d_in[20];
  const float* fcb= (const float*)d_in[21];
  float* out = (float*)d_out;

  int N   = in_sizes[2];
  int E   = in_sizes[1] / 2;
  int C   = in_sizes[21];
  int G   = out_size / C;
  float invN = 1.0f / (float)N;

  int nbk = (N + 255) >> 8;       // 256-node target buckets

  char* ws = (char*)d_ws;
  size_t off = 0;
  auto alloc = [&](size_t bytes) { size_t o = off; off = (off + bytes + 255) & ~(size_t)255; return o; };
  // zero-init group (must be first / contiguous)
  size_t o_bkc  = alloc((size_t)nbk * 4);
  size_t o_bn   = alloc(4 * 2 * 64 * 4);
  size_t o_pool = alloc((size_t)G * DIM * 4);
  size_t o_gcnt = alloc((size_t)G * 4);
  size_t zero_bytes = off;
  // no-init group
  size_t o_ko   = alloc((size_t)(nbk + 1) * 4);
  size_t o_cur  = alloc((size_t)nbk * 4);
  size_t o_offs = alloc((size_t)N * 4);
  size_t o_cnt  = alloc((size_t)N * 4);
  size_t o_dis  = alloc((size_t)N * 4);
  size_t o_recs = alloc((size_t)E * 4);
  size_t o_csr  = alloc((size_t)E * 4);
  size_t o_xl   = alloc((size_t)N * DIM * 2);   // fp16
  size_t o_y    = alloc((size_t)N * DIM * 2);   // fp16
  (void)ws_size;

  int*    bkcnt  = (int*)(ws + o_bkc);
  float*  bn     = (float*)(ws + o_bn);
  float*  pooled = (float*)(ws + o_pool);
  float*  gcnt   = (float*)(ws + o_gcnt);
  int*    keyoffs= (int*)(ws + o_ko);
  int*    bcur   = (int*)(ws + o_cur);
  int*    offs   = (int*)(ws + o_offs);
  int*    cnt    = (int*)(ws + o_cnt);
  float*  dis    = (float*)(ws + o_dis);
  uint32* recs   = (uint32*)(ws + o_recs);
  int*    csrs   = (int*)(ws + o_csr);
  f16*    xl     = (f16*)(ws + o_xl);
  f16*    y      = (f16*)(ws + o_y);

  hipMemsetAsync(d_ws, 0, zero_bytes, stream);

  const int* row  = ei;
  const int* colp = ei + E;
  int pblk = (E + PCHUNK - 1) / PCHUNK;

  k_hist<<<pblk, 256, 0, stream>>>(colp, bkcnt, E, nbk);
  k_scank<<<1, 256, 0, stream>>>(bkcnt, keyoffs, bcur, nbk);
  k_part<<<pblk, 256, 0, stream>>>(row, colp, bcur, recs, E, nbk);
  k_sort2<<<nbk, 256, 0, stream>>>(recs, keyoffs, csrs, offs, cnt, dis, N);

  // Layer 1
  k_gemm_in<<<2048, 256, 0, stream>>>(x, W1, dis, xl, N);
  k_agg<<<2048, 256, 0, stream>>>(xl, offs, cnt, csrs, dis, b1, y, bn + 0, bn + 64, N);
  // Layer 2 (applies BN1 via folded W)
  k_gemm_bn<<<2048, 256, 0, stream>>>(y, W2, g1, be1, bn + 0, bn + 64, dis, xl, N, invN);
  k_agg<<<2048, 256, 0, stream>>>(xl, offs, cnt, csrs, dis, b2, y, bn + 128, bn + 192, N);
  // Layer 3
  k_gemm_bn<<<2048, 256, 0, stream>>>(y, W3, g2, be2, bn + 128, bn + 192, dis, xl, N, invN);
  k_agg<<<2048, 256, 0, stream>>>(xl, offs, cnt, csrs, dis, b3, y, bn + 256, bn + 320, N);
  // Layer 4
  k_gemm_bn<<<2048, 256, 0, stream>>>(y, W4, g3, be3, bn + 256, bn + 320, dis, xl, N, invN);
  k_agg<<<2048, 256, 0, stream>>>(xl, offs, cnt, csrs, dis, b4, y, bn + 384, bn + 448, N);
  // Pool (applies BN4) + head
  int nwaves = 2048;
  int chunk = (N + nwaves - 1) / nwaves;
  k_pool<<<nwaves / 4, 256, 0, stream>>>(y, g4, be4, bn + 384, bn + 448, batch, pooled, gcnt, N, chunk, invN);
  k_head<<<(G + 255) / 256, 256, 0, stream>>>(pooled, gcnt, fcW, fcb, out, G, C);
}